// Round 8
// baseline (256.821 us; speedup 1.0000x reference)
//
#include <hip/hip_runtime.h>
#include <stdint.h>

#define BN   1024
#define FEATN 512
#define HDIM 256
#define TAUF 5.0f
#define EPSF 1e-8f

typedef __attribute__((ext_vector_type(8))) _Float16 half8;
typedef __attribute__((ext_vector_type(4))) float f32x4;

#if defined(__has_builtin)
#if __has_builtin(__builtin_amdgcn_rcpf)
#define HAVE_RCPF 1
#endif
#if __has_builtin(__builtin_amdgcn_exp2f)
#define HAVE_EXP2F 1
#endif
#endif

#ifdef HAVE_RCPF
__device__ __forceinline__ float fast_rcp(float x) { return __builtin_amdgcn_rcpf(x); }
#else
__device__ __forceinline__ float fast_rcp(float x) { return 1.0f / x; }
#endif

#ifdef HAVE_EXP2F
__device__ __forceinline__ float fast_exp2(float x) { return __builtin_amdgcn_exp2f(x); }
#else
__device__ __forceinline__ float fast_exp2(float x) { return exp2f(x); }
#endif

// gelu(x)*w2 via tanh-approx == x*w2*sigmoid(1.5957691x + 0.0713548x^3).
// log2e folded into the poly constants; sigmoid as 1/(1+2^q), q = -s*log2e.
#define GC1 (-0.102944544f)   // -0.07135481627 * log2(e)
#define GC2 (-2.302116228f)   // -1.59576912161 * log2(e)
__device__ __forceinline__ float gelu_w2_acc(float x, float w2, float v) {
  float t = x * x;
  float p = fmaf(t, GC1, GC2);
  float q = p * x;                  // q = -s*log2e
  float e = fast_exp2(q);
  float r = fast_rcp(e + 1.0f);     // sigmoid(s)
  return fmaf(x * w2, r, v);
}

// lgkm-only barrier (r5: neutral vs __syncthreads, never worse; keep)
#define BAR() asm volatile("s_waitcnt lgkmcnt(0)\n\ts_barrier" ::: "memory")

// ---------------- prep: W1[:512] + 17th step -> fp16 frag order; label softmax ----------------
__global__ __launch_bounds__(256) void prep_kernel(const float* __restrict__ W1,
                                                   const float* __restrict__ b1,
                                                   const float* __restrict__ lg,
                                                   _Float16* __restrict__ w1h,
                                                   float* __restrict__ oh) {
  int b = blockIdx.x, t = threadIdx.x;
  if (b < FEATN) {
    int k = b, n = t;
    // B-frag layout: element (k,n) at ((k>>3)*256 + n)*8 + (k&7)
    w1h[(((k >> 3) * HDIM) + n) * 8 + (k & 7)] = (_Float16)W1[k * HDIM + n];
  } else if (b < FEATN + 4) {
    int i = (b - FEATN) * 256 + t;
    float l0 = lg[2 * i], l1 = lg[2 * i + 1];
    float m = fmaxf(l0, l1);
    float e0 = __expf(l0 - m), e1 = __expf(l1 - m);
    float inv = 1.0f / (e0 + e1);
    oh[2 * i] = e0 * inv;
    oh[2 * i + 1] = e1 * inv;
  } else {
    // 17th B-step (kt=16): virtual K-rows {W1[512], W1[513], b1, 0...} for the
    // rank-2-label + bias fold. Same frag layout, koct = b - FEATN - 4.
    int koct = b - FEATN - 4;
    half8 hv = (half8){};
    if (koct == 0) {
      hv[0] = (_Float16)W1[512 * HDIM + t];
      hv[1] = (_Float16)W1[513 * HDIM + t];
      hv[2] = (_Float16)b1[t];
    }
    *(half8*)(w1h + 16 * 8192 + (koct * HDIM + t) * 8) = hv;
  }
}

// ---------------- main: fused pair-GEMM (fp16 MFMA) + gelu + W2-dot + sigmoid ----------------
// h_scores is SYMMETRIC -> lower-triangle tiles only (grid 65x128 rectangle folded),
// each block writes its 8x8 tile AND the shfl-transposed mirror tile.
// Round-8 isolated change: NO sA, NO K-loop barriers. Each wave builds all 4
// m-subtile A-frags privately in registers from sX (read-only after the one stage
// barrier). Trades +24 VALU/step for zero barrier lockstep + compiler freedom to
// software-pipeline xi/bfr prefetch under MFMAs. LDS 34.8 -> 18.4 KB.
// REGISTER DISCIPLINE: 64 VGPR + 64 AGPR acc = exactly 128/lane = 4 waves/SIMD.
// launch_bounds stays (256,4): (256,6) spilled the accumulator (round-3: 794 us).
__global__ __launch_bounds__(256, 4) void gemm_kernel(const float* __restrict__ X,
                                                      const _Float16* __restrict__ w1h,
                                                      const float* __restrict__ oh,
                                                      const float* __restrict__ W2,
                                                      const float* __restrict__ b2,
                                                      float* __restrict__ out_hs) {
  __shared__ __align__(16) _Float16 sX[16 * 520];     // rows 0-7: i, 8-15: j (stride 520 fp16)
  __shared__ float sScore[64 * 4];
  __shared__ float sLab0[64], sLab1[64];

  const int tid = threadIdx.x;
  const int L = tid & 63;
  const int w = tid >> 6;              // wave id == n-quarter

  // triangle fold: map grid (x in [0,65), y in [0,128)) onto lower-tri tiles (bi >= bj).
  int bi = blockIdx.y, bj = blockIdx.x;
  if (bj > bi) { bi = 127 - bi; bj = 128 - bj; }
  const int i0 = bi * 8;
  const int j0 = bj * 8;

  // ---- stage 16 X rows, f32 -> fp16 (RTNE), LDS stride 520 fp16 ----
  #pragma unroll
  for (int it = 0; it < 4; ++it) {
    int idx = tid + it * 256;          // 1024 octet tasks (16 rows x 64 octets)
    int row = idx >> 6;
    int oc = idx & 63;
    int grow = (row < 8) ? (i0 + row) : (j0 + row - 8);
    const float* gp = X + grow * FEATN + oc * 8;
    float4 a = *(const float4*)gp;
    float4 c = *(const float4*)(gp + 4);
    half8 hv;
    hv[0] = (_Float16)a.x; hv[1] = (_Float16)a.y; hv[2] = (_Float16)a.z; hv[3] = (_Float16)a.w;
    hv[4] = (_Float16)c.x; hv[5] = (_Float16)c.y; hv[6] = (_Float16)c.z; hv[7] = (_Float16)c.w;
    *(half8*)(sX + row * 520 + oc * 8) = hv;
  }
  if (tid < 64) {
    int gi = i0 + (tid >> 3), gj = j0 + (tid & 7);
    sLab0[tid] = oh[2 * gi] * oh[2 * gj];
    sLab1[tid] = oh[2 * gi + 1] * oh[2 * gj + 1];
  }

  // ---- frag decode for lane L (all 4 m-subtiles, private) ----
  // subtile s: pair m = 16s + nl; xi row = 2s + (nl>>3); xj row = 8 + (L&7); k-oct = L>>4
  const int nl = L & 15;
  const int koct = L >> 4;
  const _Float16* cxi = sX + (nl >> 3) * 520 + koct * 8;   // + s*1040
  const _Float16* cxj = sX + (8 + (L & 7)) * 520 + koct * 8;

  // B-frag per-lane base (fp16 elems): step kt at +kt*8192, n-subtile u at +u*128
  const _Float16* bbase = w1h + ((koct * HDIM) + w * 64 + nl) * 8;

  f32x4 acc[4][4];                     // written first by STEP0 (no zero-init)

  BAR();                               // sX + sLab visible; ONLY barrier before epilogue

  // one K-step: load 4 B-frags + xj, then per subtile {xi, pk-sub, abs, 4 MFMA}
  #define STEP_BODY(kt, CEXPR)                                            \
    {                                                                     \
      half8 bfr[4];                                                       \
      _Pragma("unroll")                                                   \
      for (int u = 0; u < 4; ++u)                                         \
        bfr[u] = *(const half8*)(bbase + (kt) * 8192 + u * 128);          \
      half8 xj = *(const half8*)(cxj + (kt) * 32);                        \
      _Pragma("unroll")                                                   \
      for (int s = 0; s < 4; ++s) {                                       \
        half8 xi = *(const half8*)(cxi + s * 1040 + (kt) * 32);           \
        union { half8 h; unsigned u4[4]; } U;                             \
        U.h = xi - xj;                                                    \
        U.u4[0] &= 0x7FFF7FFFu; U.u4[1] &= 0x7FFF7FFFu;                   \
        U.u4[2] &= 0x7FFF7FFFu; U.u4[3] &= 0x7FFF7FFFu;                   \
        _Pragma("unroll")                                                 \
        for (int u = 0; u < 4; ++u)                                       \
          acc[s][u] = __builtin_amdgcn_mfma_f32_16x16x32_f16(             \
              U.h, bfr[u], CEXPR, 0, 0, 0);                               \
      }                                                                   \
    }

  // kt=0 peeled: accumulators start from literal 0 (no accvgpr zero-init)
  STEP_BODY(0, ((f32x4){0.f, 0.f, 0.f, 0.f}))
  #pragma unroll 2
  for (int kt = 1; kt < 16; ++kt)
    STEP_BODY(kt, acc[s][u])
  #undef STEP_BODY

  // ---- 17th k-step: label rank-2 + bias via MFMA ----
  // A[m][512..514] = {lab0[m], lab1[m], 1.0}, zeros elsewhere (koct!=0 lanes all-zero).
  {
    half8 bfr[4];
    #pragma unroll
    for (int u = 0; u < 4; ++u)
      bfr[u] = *(const half8*)(bbase + 16 * 8192 + u * 128);
    #pragma unroll
    for (int s = 0; s < 4; ++s) {
      half8 af = (half8){};
      if (koct == 0) {
        int m = s * 16 + nl;
        af[0] = (_Float16)sLab0[m];
        af[1] = (_Float16)sLab1[m];
        af[2] = (_Float16)1.0f;
      }
      #pragma unroll
      for (int u = 0; u < 4; ++u)
        acc[s][u] = __builtin_amdgcn_mfma_f32_16x16x32_f16(af, bfr[u], acc[s][u], 0, 0, 0);
    }
  }

  // ---- epilogue: fast gelu*W2 accumulate, reduce, sigmoid ----
  const int q = L >> 4;
  float ww2[4];
  #pragma unroll
  for (int u = 0; u < 4; ++u) ww2[u] = W2[w * 64 + u * 16 + nl];
  #pragma unroll
  for (int s = 0; s < 4; ++s) {
    #pragma unroll
    for (int r = 0; r < 4; ++r) {
      int m = s * 16 + q * 4 + r;     // C/D: row = quad*4 + reg
      float v = 0.f;
      #pragma unroll
      for (int u = 0; u < 4; ++u) v = gelu_w2_acc(acc[s][u][r], ww2[u], v);
      v += __shfl_xor(v, 1, 64);
      v += __shfl_xor(v, 2, 64);
      v += __shfl_xor(v, 4, 64);
      v += __shfl_xor(v, 8, 64);       // sum over 16 lanes of the quad
      if (nl == 0) sScore[m * 4 + w] = v;
    }
  }
  BAR();
  if (tid < 64) {
    float s4 = sScore[tid * 4 + 0] + sScore[tid * 4 + 1] + sScore[tid * 4 + 2] +
               sScore[tid * 4 + 3] + b2[0];
    float e = fast_exp2(s4 * -1.4426950408889634f);
    float hsv = fast_rcp(1.0f + e);
    int r = tid >> 3, c = tid & 7;
    out_hs[(size_t)(i0 + r) * BN + (j0 + c)] = hsv;
    if (i0 != j0) {
      // mirror tile: element (j0+r, i0+c) = hsv of pair (i0+c, j0+r) = lane (c*8+r)
      float tv = __shfl(hsv, (c << 3) | r, 64);
      out_hs[(size_t)(j0 + r) * BN + (i0 + c)] = tv;
    }
  }
}

// ---------------- row softmax of adj + TAU*log(hs + EPS) ----------------
__global__ __launch_bounds__(256) void softmax_kernel(const float* __restrict__ adj,
                                                      const float* __restrict__ hs,
                                                      float* __restrict__ out) {
  int i = blockIdx.x, t = threadIdx.x;
  __shared__ float redm[4];
  __shared__ float reds[4];
  const float TAUL2 = TAUF * 0.69314718056f;   // TAU*log(h) = (TAU*ln2)*log2(h)
  float l[4];
  float mx = -1e30f;
  #pragma unroll
  for (int k = 0; k < 4; ++k) {
    int j = t + k * 256;
    float lv = adj[(size_t)i * BN + j] + TAUL2 * __log2f(hs[(size_t)i * BN + j] + EPSF);
    l[k] = lv;
    mx = fmaxf(mx, lv);
  }
  #pragma unroll
  for (int o = 1; o <= 32; o <<= 1) mx = fmaxf(mx, __shfl_xor(mx, o, 64));
  if ((t & 63) == 0) redm[t >> 6] = mx;
  __syncthreads();
  mx = fmaxf(fmaxf(redm[0], redm[1]), fmaxf(redm[2], redm[3]));
  float ex[4];
  float se = 0.f;
  #pragma unroll
  for (int k = 0; k < 4; ++k) { ex[k] = __expf(l[k] - mx); se += ex[k]; }
  #pragma unroll
  for (int o = 1; o <= 32; o <<= 1) se += __shfl_xor(se, o, 64);
  if ((t & 63) == 0) reds[t >> 6] = se;
  __syncthreads();
  se = reds[0] + reds[1] + reds[2] + reds[3];
  float inv = fast_rcp(se);
  #pragma unroll
  for (int k = 0; k < 4; ++k) out[(size_t)i * BN + t + k * 256] = ex[k] * inv;
}

extern "C" void kernel_launch(void* const* d_in, const int* in_sizes, int n_in,
                              void* d_out, int out_size, void* d_ws, size_t ws_size,
                              hipStream_t stream) {
  (void)in_sizes; (void)n_in; (void)out_size; (void)ws_size;
  const float* X   = (const float*)d_in[0];
  const float* lg  = (const float*)d_in[1];
  const float* adj = (const float*)d_in[2];
  const float* W1  = (const float*)d_in[3];
  const float* b1  = (const float*)d_in[4];
  const float* W2  = (const float*)d_in[5];
  const float* b2  = (const float*)d_in[6];
  float* out = (float*)d_out;                       // [0,B^2): adj_refined, [B^2,2B^2): h_scores
  _Float16* w1h = (_Float16*)d_ws;                  // 17*8192 fp16 = 272 KB (16 steps + label/bias step)
  float* oh = (float*)((char*)d_ws + 17 * 8192 * 2);  // 1024*2 f32

  float* out_hs = out + (size_t)BN * BN;

  prep_kernel<<<dim3(FEATN + 8), dim3(256), 0, stream>>>(W1, b1, lg, w1h, oh);
  // lower-triangle tiles only (h_scores is symmetric): 65x128 rectangle folds onto triangle
  gemm_kernel<<<dim3(65, 128), dim3(256), 0, stream>>>(X, w1h, oh, W2, b2, out_hs);
  softmax_kernel<<<dim3(BN), dim3(256), 0, stream>>>(adj, out_hs, out);
}

// Round 11
// 248.971 us; speedup vs baseline: 1.0315x; 1.0315x over previous
//
#include <hip/hip_runtime.h>
#include <stdint.h>

#define BN   1024
#define FEATN 512
#define HDIM 256
#define TAUF 5.0f
#define EPSF 1e-8f

typedef __attribute__((ext_vector_type(8))) _Float16 half8;
typedef __attribute__((ext_vector_type(4))) float f32x4;

#if defined(__has_builtin)
#if __has_builtin(__builtin_amdgcn_rcpf)
#define HAVE_RCPF 1
#endif
#if __has_builtin(__builtin_amdgcn_exp2f)
#define HAVE_EXP2F 1
#endif
#endif

#ifdef HAVE_RCPF
__device__ __forceinline__ float fast_rcp(float x) { return __builtin_amdgcn_rcpf(x); }
#else
__device__ __forceinline__ float fast_rcp(float x) { return 1.0f / x; }
#endif

#ifdef HAVE_EXP2F
__device__ __forceinline__ float fast_exp2(float x) { return __builtin_amdgcn_exp2f(x); }
#else
__device__ __forceinline__ float fast_exp2(float x) { return exp2f(x); }
#endif

// gelu(x)*w2 via tanh-approx == x*w2*sigmoid(1.5957691x + 0.0713548x^3).
// log2e folded into the poly constants; sigmoid as 1/(1+2^q), q = -s*log2e.
// (Scalar form — the v_pk_f32 asm path failed correctness twice (r9/r10); abandoned.)
#define GC1 (-0.102944544f)   // -0.07135481627 * log2(e)
#define GC2 (-2.302116228f)   // -1.59576912161 * log2(e)
__device__ __forceinline__ float gelu_w2_acc(float x, float w2, float v) {
  float t = x * x;
  float p = fmaf(t, GC1, GC2);
  float q = p * x;                  // q = -s*log2e
  float e = fast_exp2(q);
  float r = fast_rcp(e + 1.0f);     // sigmoid(s)
  return fmaf(x * w2, r, v);
}

// lgkm-only barrier (r5: neutral vs __syncthreads, never worse; keep)
#define BAR() asm volatile("s_waitcnt lgkmcnt(0)\n\ts_barrier" ::: "memory")

// ---------------- prep: W1[:512] + 17th step -> fp16 frag order; label softmax ----------------
__global__ __launch_bounds__(256) void prep_kernel(const float* __restrict__ W1,
                                                   const float* __restrict__ b1,
                                                   const float* __restrict__ lg,
                                                   _Float16* __restrict__ w1h,
                                                   float* __restrict__ oh) {
  int b = blockIdx.x, t = threadIdx.x;
  if (b < FEATN) {
    int k = b, n = t;
    // B-frag layout: element (k,n) at ((k>>3)*256 + n)*8 + (k&7)
    w1h[(((k >> 3) * HDIM) + n) * 8 + (k & 7)] = (_Float16)W1[k * HDIM + n];
  } else if (b < FEATN + 4) {
    int i = (b - FEATN) * 256 + t;
    float l0 = lg[2 * i], l1 = lg[2 * i + 1];
    float m = fmaxf(l0, l1);
    float e0 = __expf(l0 - m), e1 = __expf(l1 - m);
    float inv = 1.0f / (e0 + e1);
    oh[2 * i] = e0 * inv;
    oh[2 * i + 1] = e1 * inv;
  } else {
    // 17th B-step (kt=16): virtual K-rows {W1[512], W1[513], b1, 0...} for the
    // rank-2-label + bias fold. Same frag layout, koct = b - FEATN - 4.
    int koct = b - FEATN - 4;
    half8 hv = (half8){};
    if (koct == 0) {
      hv[0] = (_Float16)W1[512 * HDIM + t];
      hv[1] = (_Float16)W1[513 * HDIM + t];
      hv[2] = (_Float16)b1[t];
    }
    *(half8*)(w1h + 16 * 8192 + (koct * HDIM + t) * 8) = hv;
  }
}

// ---------------- main: fused pair-GEMM (fp16 MFMA) + gelu + W2-dot + sigmoid ----------------
// Round-11 change: 16i x 8j tile (128 pairs), 512 threads / 8 waves. Rationale: r7's
// B-fragment L2 traffic was 272KB/block x 8320 blocks = 13.5 TB/s = ~92% of the
// per-CU L2 load ceiling (~56 B/cyc/CU) -- the hidden saturated pipe. Doubling M per
// B-read halves B traffic per pair. Wave w covers n-eighth [32w,32w+32) (u=0,1) x all
// 8 m-subtiles; constructs m-subtile w. acc = 8x2xf32x4 = 64 AGPR (unchanged budget).
// LDS 62.8KB -> 2 blocks/CU x 8 waves = 4 waves/SIMD (same occupancy as r7).
// h symmetric -> mirror write needs NO shuffle: same hsv to (j,i). Cross-block
// duplicate writes are bitwise identical (abs-mask makes |xi-xj| exactly symmetric).
// REGISTER DISCIPLINE: total 128/lane cap via launch_bounds(512,4); CONSUME split
// into two 4-subtile halves to keep transients ~24 VGPR. If VGPR>64: revert.
__global__ __launch_bounds__(512, 4) void gemm_kernel(const float* __restrict__ X,
                                                      const _Float16* __restrict__ w1h,
                                                      const float* __restrict__ oh,
                                                      const float* __restrict__ W2,
                                                      const float* __restrict__ b2,
                                                      float* __restrict__ out_hs) {
  __shared__ __align__(16) _Float16 sX[24 * 520];     // rows 0-15: i, 16-23: j
  __shared__ __align__(16) half8 sA[2][2][8][64];     // [buf][step][m-subtile][lane] 32KB
  __shared__ float sScore[128 * 8];
  __shared__ float sLab0[128], sLab1[128];

  const int tid = threadIdx.x;
  const int L = tid & 63;
  const int w = tid >> 6;              // wave id 0..7 == n-eighth AND construct m-subtile

  // triangle fold: grid (x in [0,65), y in [0,64)) -> lower-tri 16x8 tiles.
  // Tile (bi,bj) needed iff bj <= 2*bi+1. Bijective: 65*64 = 4160 = sum(2bi+2).
  int x = blockIdx.x, y = blockIdx.y;
  int bi, bj;
  if (x <= 2 * y + 1) { bi = y; bj = x; }
  else { bi = 63 - y; bj = 129 - x; }
  const int i0 = bi * 16;
  const int j0 = bj * 8;

  // ---- stage 24 X rows, f32 -> fp16 (RTNE), LDS stride 520 fp16 ----
  #pragma unroll
  for (int it = 0; it < 3; ++it) {
    int idx = tid + it * 512;          // 1536 octet tasks (24 rows x 64 octets)
    int row = idx >> 6;
    int oc = idx & 63;
    int grow = (row < 16) ? (i0 + row) : (j0 + row - 16);
    const float* gp = X + grow * FEATN + oc * 8;
    float4 a = *(const float4*)gp;
    float4 c = *(const float4*)(gp + 4);
    half8 hv;
    hv[0] = (_Float16)a.x; hv[1] = (_Float16)a.y; hv[2] = (_Float16)a.z; hv[3] = (_Float16)a.w;
    hv[4] = (_Float16)c.x; hv[5] = (_Float16)c.y; hv[6] = (_Float16)c.z; hv[7] = (_Float16)c.w;
    *(half8*)(sX + row * 520 + oc * 8) = hv;
  }
  if (tid < 128) {
    int gi = i0 + (tid >> 3), gj = j0 + (tid & 7);
    sLab0[tid] = oh[2 * gi] * oh[2 * gj];
    sLab1[tid] = oh[2 * gi + 1] * oh[2 * gj + 1];
  }

  // ---- construct decode: wave w builds m-subtile w's frag for lane L ----
  // subtile s: pairs m = 16s + nl; i-row = 2s + (nl>>3); j-row = 16 + (L&7); koct = L>>4
  const int nl = L & 15;
  const int koct = L >> 4;
  const _Float16* cxi = sX + (2 * w + (nl >> 3)) * 520 + koct * 8;
  const _Float16* cxj = sX + (16 + (L & 7)) * 520 + koct * 8;

  // B-frag per-lane base: wave w covers n in [32w, 32w+32): n = 32w + 16u + nl.
  // offset(kt, u) = kt*8192 + u*128 (fp16 elems)
  const _Float16* bbase = w1h + ((koct * HDIM) + 32 * w + nl) * 8;

  f32x4 acc[8][2];                     // written first by CONSUME0 (no zero-init)

  BAR();

  // construct one step's A-frag (fp16 pk-sub + abs mask) into sA[buf][st][w]
  #define CONSTRUCT(kt, buf, st)                                          \
    {                                                                     \
      half8 xi = *(const half8*)(cxi + (kt) * 32);                        \
      half8 xj = *(const half8*)(cxj + (kt) * 32);                        \
      union { half8 h; unsigned u4[4]; } U;                               \
      U.h = xi - xj;                                                      \
      U.u4[0] &= 0x7FFF7FFFu; U.u4[1] &= 0x7FFF7FFFu;                     \
      U.u4[2] &= 0x7FFF7FFFu; U.u4[3] &= 0x7FFF7FFFu;                     \
      sA[buf][st][w][L] = U.h;                                            \
    }

  // consume: 2 B-frags, 8 A-frags in two halves (transient cap ~24 VGPR)
  #define CONSUME_BODY(kt, buf, st, CEXPR0, CEXPR)                        \
    {                                                                     \
      half8 bfr[2];                                                       \
      bfr[0] = *(const half8*)(bbase + (kt) * 8192);                      \
      bfr[1] = *(const half8*)(bbase + (kt) * 8192 + 128);                \
      half8 af0[4];                                                       \
      _Pragma("unroll")                                                   \
      for (int s = 0; s < 4; ++s) af0[s] = sA[buf][st][s][L];             \
      _Pragma("unroll")                                                   \
      for (int s = 0; s < 4; ++s)                                         \
        _Pragma("unroll")                                                 \
        for (int u = 0; u < 2; ++u)                                       \
          acc[s][u] = __builtin_amdgcn_mfma_f32_16x16x32_f16(             \
              af0[s], bfr[u], CEXPR0, 0, 0, 0);                           \
      half8 af1[4];                                                       \
      _Pragma("unroll")                                                   \
      for (int s = 0; s < 4; ++s) af1[s] = sA[buf][st][4 + s][L];         \
      _Pragma("unroll")                                                   \
      for (int s = 0; s < 4; ++s)                                         \
        _Pragma("unroll")                                                 \
        for (int u = 0; u < 2; ++u)                                       \
          acc[4 + s][u] = __builtin_amdgcn_mfma_f32_16x16x32_f16(         \
              af1[s], bfr[u], CEXPR, 0, 0, 0);                            \
    }

  #define CONSUME(kt, buf, st)                                            \
    CONSUME_BODY(kt, buf, st, acc[s][u], acc[4 + s][u])
  #define CONSUME0(kt, buf, st)                                           \
    CONSUME_BODY(kt, buf, st, ((f32x4){0.f, 0.f, 0.f, 0.f}),              \
                 ((f32x4){0.f, 0.f, 0.f, 0.f}))

  // prologue: chunk 0 (steps 0,1)
  CONSTRUCT(0, 0, 0)
  CONSTRUCT(1, 0, 1)
  BAR();

  // t=0 peeled: step-0 MFMA starts accumulators from literal 0
  CONSUME0(0, 0, 0)
  CONSUME(1, 0, 1)
  CONSTRUCT(2, 1, 0)
  CONSTRUCT(3, 1, 1)
  BAR();

  #pragma unroll 2
  for (int t = 1; t < 8; ++t) {
    const int buf = t & 1;
    CONSUME(2 * t, buf, 0)
    CONSUME(2 * t + 1, buf, 1)
    if (t < 7) {
      CONSTRUCT(2 * t + 2, 1 - buf, 0)
      CONSTRUCT(2 * t + 3, 1 - buf, 1)
    }
    BAR();
  }
  #undef CONSTRUCT
  #undef CONSUME
  #undef CONSUME0
  #undef CONSUME_BODY

  // ---- 17th k-step: label rank-2 + bias via MFMA ----
  // A[m][512..514] = {lab0[m], lab1[m], 1.0}, zeros elsewhere (koct!=0 lanes all-zero).
  {
    half8 bfr[2];
    bfr[0] = *(const half8*)(bbase + 16 * 8192);
    bfr[1] = *(const half8*)(bbase + 16 * 8192 + 128);
    #pragma unroll
    for (int s = 0; s < 8; ++s) {
      half8 af = (half8){};
      if (koct == 0) {
        int m = s * 16 + nl;
        af[0] = (_Float16)sLab0[m];
        af[1] = (_Float16)sLab1[m];
        af[2] = (_Float16)1.0f;
      }
      #pragma unroll
      for (int u = 0; u < 2; ++u)
        acc[s][u] = __builtin_amdgcn_mfma_f32_16x16x32_f16(af, bfr[u], acc[s][u], 0, 0, 0);
    }
  }

  // ---- epilogue: fast gelu*W2 accumulate, reduce, sigmoid ----
  const int q = L >> 4;
  float ww2[2];
  #pragma unroll
  for (int u = 0; u < 2; ++u) ww2[u] = W2[32 * w + u * 16 + nl];
  #pragma unroll
  for (int s = 0; s < 8; ++s) {
    #pragma unroll
    for (int r = 0; r < 4; ++r) {
      int m = s * 16 + q * 4 + r;     // C/D: row = quad*4 + reg
      float v = 0.f;
      #pragma unroll
      for (int u = 0; u < 2; ++u) v = gelu_w2_acc(acc[s][u][r], ww2[u], v);
      v += __shfl_xor(v, 1, 64);
      v += __shfl_xor(v, 2, 64);
      v += __shfl_xor(v, 4, 64);
      v += __shfl_xor(v, 8, 64);       // sum over 16 lanes of the quad
      if (nl == 0) sScore[m * 8 + w] = v;
    }
  }
  BAR();
  if (tid < 128) {
    float s8 = sScore[tid * 8 + 0] + sScore[tid * 8 + 1] + sScore[tid * 8 + 2] +
               sScore[tid * 8 + 3] + sScore[tid * 8 + 4] + sScore[tid * 8 + 5] +
               sScore[tid * 8 + 6] + sScore[tid * 8 + 7] + b2[0];
    float e = fast_exp2(s8 * -1.4426950408889634f);
    float hsv = fast_rcp(1.0f + e);
    int r = tid >> 3, c = tid & 7;
    out_hs[(size_t)(i0 + r) * BN + (j0 + c)] = hsv;
    // mirror: h symmetric -> same value at (j,i). Duplicate writes across blocks
    // are bitwise identical (abs-mask), hence benign.
    out_hs[(size_t)(j0 + c) * BN + (i0 + r)] = hsv;
  }
}

// ---------------- row softmax of adj + TAU*log(hs + EPS) ----------------
__global__ __launch_bounds__(256) void softmax_kernel(const float* __restrict__ adj,
                                                      const float* __restrict__ hs,
                                                      float* __restrict__ out) {
  int i = blockIdx.x, t = threadIdx.x;
  __shared__ float redm[4];
  __shared__ float reds[4];
  const float TAUL2 = TAUF * 0.69314718056f;   // TAU*log(h) = (TAU*ln2)*log2(h)
  float l[4];
  float mx = -1e30f;
  #pragma unroll
  for (int k = 0; k < 4; ++k) {
    int j = t + k * 256;
    float lv = adj[(size_t)i * BN + j] + TAUL2 * __log2f(hs[(size_t)i * BN + j] + EPSF);
    l[k] = lv;
    mx = fmaxf(mx, lv);
  }
  #pragma unroll
  for (int o = 1; o <= 32; o <<= 1) mx = fmaxf(mx, __shfl_xor(mx, o, 64));
  if ((t & 63) == 0) redm[t >> 6] = mx;
  __syncthreads();
  mx = fmaxf(fmaxf(redm[0], redm[1]), fmaxf(redm[2], redm[3]));
  float ex[4];
  float se = 0.f;
  #pragma unroll
  for (int k = 0; k < 4; ++k) { ex[k] = __expf(l[k] - mx); se += ex[k]; }
  #pragma unroll
  for (int o = 1; o <= 32; o <<= 1) se += __shfl_xor(se, o, 64);
  if ((t & 63) == 0) reds[t >> 6] = se;
  __syncthreads();
  se = reds[0] + reds[1] + reds[2] + reds[3];
  float inv = fast_rcp(se);
  #pragma unroll
  for (int k = 0; k < 4; ++k) out[(size_t)i * BN + t + k * 256] = ex[k] * inv;
}

extern "C" void kernel_launch(void* const* d_in, const int* in_sizes, int n_in,
                              void* d_out, int out_size, void* d_ws, size_t ws_size,
                              hipStream_t stream) {
  (void)in_sizes; (void)n_in; (void)out_size; (void)ws_size;
  const float* X   = (const float*)d_in[0];
  const float* lg  = (const float*)d_in[1];
  const float* adj = (const float*)d_in[2];
  const float* W1  = (const float*)d_in[3];
  const float* b1  = (const float*)d_in[4];
  const float* W2  = (const float*)d_in[5];
  const float* b2  = (const float*)d_in[6];
  float* out = (float*)d_out;                       // [0,B^2): adj_refined, [B^2,2B^2): h_scores
  _Float16* w1h = (_Float16*)d_ws;                  // 17*8192 fp16 = 272 KB (16 steps + label/bias step)
  float* oh = (float*)((char*)d_ws + 17 * 8192 * 2);  // 1024*2 f32

  float* out_hs = out + (size_t)BN * BN;

  prep_kernel<<<dim3(FEATN + 8), dim3(256), 0, stream>>>(W1, b1, lg, w1h, oh);
  // lower-triangle 16x8 tiles, bijective 65x64 fold (no seam duplicates)
  gemm_kernel<<<dim3(65, 64), dim3(512), 0, stream>>>(X, w1h, oh, W2, b2, out_hs);
  softmax_kernel<<<dim3(BN), dim3(256), 0, stream>>>(adj, out_hs, out);
}

// Round 12
// 239.183 us; speedup vs baseline: 1.0737x; 1.0409x over previous
//
#include <hip/hip_runtime.h>
#include <stdint.h>

#define BN   1024
#define FEATN 512
#define HDIM 256
#define TAUF 5.0f
#define EPSF 1e-8f

typedef __attribute__((ext_vector_type(8))) _Float16 half8;
typedef __attribute__((ext_vector_type(4))) float f32x4;

#if defined(__has_builtin)
#if __has_builtin(__builtin_amdgcn_rcpf)
#define HAVE_RCPF 1
#endif
#if __has_builtin(__builtin_amdgcn_exp2f)
#define HAVE_EXP2F 1
#endif
#endif

#ifdef HAVE_RCPF
__device__ __forceinline__ float fast_rcp(float x) { return __builtin_amdgcn_rcpf(x); }
#else
__device__ __forceinline__ float fast_rcp(float x) { return 1.0f / x; }
#endif

#ifdef HAVE_EXP2F
__device__ __forceinline__ float fast_exp2(float x) { return __builtin_amdgcn_exp2f(x); }
#else
__device__ __forceinline__ float fast_exp2(float x) { return exp2f(x); }
#endif

// gelu(x)*w2 via tanh-approx == x*w2*sigmoid(1.5957691x + 0.0713548x^3).
// log2e folded into the poly constants; sigmoid as 1/(1+2^q), q = -s*log2e.
// (Scalar form — the v_pk_f32 asm path failed correctness twice (r9/r10); abandoned.)
#define GC1 (-0.102944544f)   // -0.07135481627 * log2(e)
#define GC2 (-2.302116228f)   // -1.59576912161 * log2(e)
__device__ __forceinline__ float gelu_w2_acc(float x, float w2, float v) {
  float t = x * x;
  float p = fmaf(t, GC1, GC2);
  float q = p * x;                  // q = -s*log2e
  float e = fast_exp2(q);
  float r = fast_rcp(e + 1.0f);     // sigmoid(s)
  return fmaf(x * w2, r, v);
}

// lgkm-only barrier (r5: neutral vs __syncthreads, never worse; keep)
#define BAR() asm volatile("s_waitcnt lgkmcnt(0)\n\ts_barrier" ::: "memory")

// ---------------- prep: W1[:512] + 17th step -> fp16 frag order; label softmax ----------------
// Round-12: coalesced rewrite. Block b<64 = k-octet: thread t = column n gathers 8
// strided W1 rows (coalesced across threads per row) and stores ONE contiguous 16B
// half8 (old version wrote 2B at 16B stride -> 64 cache lines per wave store).
// 520 blocks -> 72.
__global__ __launch_bounds__(256) void prep_kernel(const float* __restrict__ W1,
                                                   const float* __restrict__ b1,
                                                   const float* __restrict__ lg,
                                                   _Float16* __restrict__ w1h,
                                                   float* __restrict__ oh) {
  int b = blockIdx.x, t = threadIdx.x;
  if (b < 64) {
    // B-frag layout: element (k,n) at ((k>>3)*256 + n)*8 + (k&7); k = 8b+e, n = t.
    const float* src = W1 + (b * 8) * HDIM + t;
    half8 hv;
    #pragma unroll
    for (int e = 0; e < 8; ++e) hv[e] = (_Float16)src[e * HDIM];
    *(half8*)(w1h + ((b * HDIM) + t) * 8) = hv;
  } else if (b < 68) {
    int i = (b - 64) * 256 + t;
    float l0 = lg[2 * i], l1 = lg[2 * i + 1];
    float m = fmaxf(l0, l1);
    float e0 = __expf(l0 - m), e1 = __expf(l1 - m);
    float inv = 1.0f / (e0 + e1);
    oh[2 * i] = e0 * inv;
    oh[2 * i + 1] = e1 * inv;
  } else {
    // 17th B-step (kt=16): virtual K-rows {W1[512], W1[513], b1, 0...} for the
    // rank-2-label + bias fold. koct = b - 68.
    int koct = b - 68;
    half8 hv = (half8){};
    if (koct == 0) {
      hv[0] = (_Float16)W1[512 * HDIM + t];
      hv[1] = (_Float16)W1[513 * HDIM + t];
      hv[2] = (_Float16)b1[t];
    }
    *(half8*)(w1h + 16 * 8192 + (koct * HDIM + t) * 8) = hv;
  }
}

// ---------------- main: fused pair-GEMM (fp16 MFMA) + gelu + W2-dot + sigmoid ----------------
// h_scores is SYMMETRIC -> lower-triangle tiles only (grid 65x128 rectangle folded),
// each block writes its 8x8 tile AND the shfl-transposed mirror tile.
// == r7 champion, byte-identical (171.5 us) ==
// Settled structure facts (measured this session):
//   - sA-shared construct + 9 lgkm barriers/K-loop beats barrier-free private
//     construct (r8: +19 us) and beats 16x8 tile @ 2 blocks/CU (r11: +27 us).
//   - Occupancy is register-limited: 64 VGPR + 64 AGPR acc = 128/lane = 4 waves/SIMD.
//     launch_bounds must stay (256,4); (256,6) spills the accumulator (r3: 794 us).
//   - 17th-MFMA-step label/bias fold and 8-op gelu epilogue: verified wins (r6/r7).
__global__ __launch_bounds__(256, 4) void gemm_kernel(const float* __restrict__ X,
                                                      const _Float16* __restrict__ w1h,
                                                      const float* __restrict__ oh,
                                                      const float* __restrict__ W2,
                                                      const float* __restrict__ b2,
                                                      float* __restrict__ out_hs) {
  __shared__ __align__(16) _Float16 sX[16 * 520];     // rows 0-7: i, 8-15: j (stride 520 fp16)
  __shared__ __align__(16) half8 sA[2][2][4][64];     // [buf][step-in-chunk][m-subtile][lane]
  __shared__ float sScore[64 * 4];
  __shared__ float sLab0[64], sLab1[64];

  const int tid = threadIdx.x;
  const int L = tid & 63;
  const int w = tid >> 6;              // wave id == n-quarter AND construct m-subtile

  // triangle fold: map grid (x in [0,65), y in [0,128)) onto lower-tri tiles (bi >= bj).
  int bi = blockIdx.y, bj = blockIdx.x;
  if (bj > bi) { bi = 127 - bi; bj = 128 - bj; }
  const int i0 = bi * 8;
  const int j0 = bj * 8;

  // ---- stage 16 X rows, f32 -> fp16 (RTNE), LDS stride 520 fp16 ----
  #pragma unroll
  for (int it = 0; it < 4; ++it) {
    int idx = tid + it * 256;          // 1024 octet tasks (16 rows x 64 octets)
    int row = idx >> 6;
    int oc = idx & 63;
    int grow = (row < 8) ? (i0 + row) : (j0 + row - 8);
    const float* gp = X + grow * FEATN + oc * 8;
    float4 a = *(const float4*)gp;
    float4 c = *(const float4*)(gp + 4);
    half8 hv;
    hv[0] = (_Float16)a.x; hv[1] = (_Float16)a.y; hv[2] = (_Float16)a.z; hv[3] = (_Float16)a.w;
    hv[4] = (_Float16)c.x; hv[5] = (_Float16)c.y; hv[6] = (_Float16)c.z; hv[7] = (_Float16)c.w;
    *(half8*)(sX + row * 520 + oc * 8) = hv;
  }
  if (tid < 64) {
    int gi = i0 + (tid >> 3), gj = j0 + (tid & 7);
    sLab0[tid] = oh[2 * gi] * oh[2 * gj];
    sLab1[tid] = oh[2 * gi + 1] * oh[2 * gj + 1];
  }

  // ---- construct decode: wave w builds m-subtile w's frag for lane L ----
  // pair m = 16w + (L&15); ii = 2w + ((L&15)>>3); jj = L&7; koct = L>>4
  const int nl = L & 15;
  const int koct = L >> 4;
  const _Float16* cxi = sX + (2 * w + (nl >> 3)) * 520 + koct * 8;
  const _Float16* cxj = sX + (8 + (L & 7)) * 520 + koct * 8;

  // B-frag per-lane base (fp16 elems): step kt at +kt*8192, n-subtile u at +u*128
  const _Float16* bbase = w1h + ((koct * HDIM) + w * 64 + nl) * 8;

  f32x4 acc[4][4];                     // written first by CONSUME0 (no zero-init)

  BAR();

  // construct one step's A-frag (fp16 pk-sub + abs mask) into sA[buf][st]
  #define CONSTRUCT(kt, buf, st)                                          \
    {                                                                     \
      half8 xi = *(const half8*)(cxi + (kt) * 32);                        \
      half8 xj = *(const half8*)(cxj + (kt) * 32);                        \
      union { half8 h; unsigned u4[4]; } U;                               \
      U.h = xi - xj;                                                      \
      U.u4[0] &= 0x7FFF7FFFu; U.u4[1] &= 0x7FFF7FFFu;                     \
      U.u4[2] &= 0x7FFF7FFFu; U.u4[3] &= 0x7FFF7FFFu;                     \
      sA[buf][st][w][L] = U.h;                                            \
    }

  #define CONSUME_BODY(kt, buf, st, CEXPR)                                \
    {                                                                     \
      half8 afr[4];                                                       \
      _Pragma("unroll")                                                   \
      for (int s = 0; s < 4; ++s) afr[s] = sA[buf][st][s][L];             \
      half8 bfr[4];                                                       \
      _Pragma("unroll")                                                   \
      for (int u = 0; u < 4; ++u)                                         \
        bfr[u] = *(const half8*)(bbase + (kt) * 8192 + u * 128);          \
      _Pragma("unroll")                                                   \
      for (int s = 0; s < 4; ++s)                                         \
        _Pragma("unroll")                                                 \
        for (int u = 0; u < 4; ++u)                                       \
          acc[s][u] = __builtin_amdgcn_mfma_f32_16x16x32_f16(             \
              afr[s], bfr[u], CEXPR, 0, 0, 0);                            \
    }

  #define CONSUME(kt, buf, st)  CONSUME_BODY(kt, buf, st, acc[s][u])
  #define CONSUME0(kt, buf, st) CONSUME_BODY(kt, buf, st, ((f32x4){0.f, 0.f, 0.f, 0.f}))

  // prologue: chunk 0 (steps 0,1)
  CONSTRUCT(0, 0, 0)
  CONSTRUCT(1, 0, 1)
  BAR();

  // t=0 peeled: step-0 MFMA starts accumulators from literal 0
  CONSUME0(0, 0, 0)
  CONSUME(1, 0, 1)
  CONSTRUCT(2, 1, 0)
  CONSTRUCT(3, 1, 1)
  BAR();

  #pragma unroll 2
  for (int t = 1; t < 8; ++t) {
    const int buf = t & 1;
    CONSUME(2 * t, buf, 0)
    CONSUME(2 * t + 1, buf, 1)
    if (t < 7) {
      CONSTRUCT(2 * t + 2, 1 - buf, 0)
      CONSTRUCT(2 * t + 3, 1 - buf, 1)
    }
    BAR();
  }
  #undef CONSTRUCT
  #undef CONSUME
  #undef CONSUME0
  #undef CONSUME_BODY

  // ---- 17th k-step: label rank-2 + bias via MFMA ----
  // A[m][512..514] = {lab0[m], lab1[m], 1.0}, zeros elsewhere (koct!=0 lanes all-zero).
  {
    half8 bfr[4];
    #pragma unroll
    for (int u = 0; u < 4; ++u)
      bfr[u] = *(const half8*)(bbase + 16 * 8192 + u * 128);
    #pragma unroll
    for (int s = 0; s < 4; ++s) {
      half8 af = (half8){};
      if (koct == 0) {
        int m = s * 16 + nl;
        af[0] = (_Float16)sLab0[m];
        af[1] = (_Float16)sLab1[m];
        af[2] = (_Float16)1.0f;
      }
      #pragma unroll
      for (int u = 0; u < 4; ++u)
        acc[s][u] = __builtin_amdgcn_mfma_f32_16x16x32_f16(af, bfr[u], acc[s][u], 0, 0, 0);
    }
  }

  // ---- epilogue: fast gelu*W2 accumulate, reduce, sigmoid ----
  const int q = L >> 4;
  float ww2[4];
  #pragma unroll
  for (int u = 0; u < 4; ++u) ww2[u] = W2[w * 64 + u * 16 + nl];
  #pragma unroll
  for (int s = 0; s < 4; ++s) {
    #pragma unroll
    for (int r = 0; r < 4; ++r) {
      int m = s * 16 + q * 4 + r;     // C/D: row = quad*4 + reg
      float v = 0.f;
      #pragma unroll
      for (int u = 0; u < 4; ++u) v = gelu_w2_acc(acc[s][u][r], ww2[u], v);
      v += __shfl_xor(v, 1, 64);
      v += __shfl_xor(v, 2, 64);
      v += __shfl_xor(v, 4, 64);
      v += __shfl_xor(v, 8, 64);       // sum over 16 lanes of the quad
      if (nl == 0) sScore[m * 4 + w] = v;
    }
  }
  BAR();
  if (tid < 64) {
    float s4 = sScore[tid * 4 + 0] + sScore[tid * 4 + 1] + sScore[tid * 4 + 2] +
               sScore[tid * 4 + 3] + b2[0];
    float e = fast_exp2(s4 * -1.4426950408889634f);
    float hsv = fast_rcp(1.0f + e);
    int r = tid >> 3, c = tid & 7;
    out_hs[(size_t)(i0 + r) * BN + (j0 + c)] = hsv;
    if (i0 != j0) {
      // mirror tile: element (j0+r, i0+c) = hsv of pair (i0+c, j0+r) = lane (c*8+r)
      float tv = __shfl(hsv, (c << 3) | r, 64);
      out_hs[(size_t)(j0 + r) * BN + (i0 + c)] = tv;
    }
  }
}

// ---------------- row softmax of adj + TAU*log(hs + EPS) ----------------
// Round-12: float4 loads/stores (j = 4t+k layout; old scalar version issued 8 dword
// loads per thread). Max reduction exact; sum association differs by ~1 ulp.
__global__ __launch_bounds__(256) void softmax_kernel(const float* __restrict__ adj,
                                                      const float* __restrict__ hs,
                                                      float* __restrict__ out) {
  int i = blockIdx.x, t = threadIdx.x;
  __shared__ float redm[4];
  __shared__ float reds[4];
  const float TAUL2 = TAUF * 0.69314718056f;   // TAU*log(h) = (TAU*ln2)*log2(h)
  const float4 av = *(const float4*)(adj + (size_t)i * BN + t * 4);
  const float4 hv = *(const float4*)(hs + (size_t)i * BN + t * 4);
  float l[4];
  l[0] = av.x + TAUL2 * __log2f(hv.x + EPSF);
  l[1] = av.y + TAUL2 * __log2f(hv.y + EPSF);
  l[2] = av.z + TAUL2 * __log2f(hv.z + EPSF);
  l[3] = av.w + TAUL2 * __log2f(hv.w + EPSF);
  float mx = fmaxf(fmaxf(l[0], l[1]), fmaxf(l[2], l[3]));
  #pragma unroll
  for (int o = 1; o <= 32; o <<= 1) mx = fmaxf(mx, __shfl_xor(mx, o, 64));
  if ((t & 63) == 0) redm[t >> 6] = mx;
  __syncthreads();
  mx = fmaxf(fmaxf(redm[0], redm[1]), fmaxf(redm[2], redm[3]));
  float ex[4];
  float se = 0.f;
  #pragma unroll
  for (int k = 0; k < 4; ++k) { ex[k] = __expf(l[k] - mx); se += ex[k]; }
  #pragma unroll
  for (int o = 1; o <= 32; o <<= 1) se += __shfl_xor(se, o, 64);
  if ((t & 63) == 0) reds[t >> 6] = se;
  __syncthreads();
  se = reds[0] + reds[1] + reds[2] + reds[3];
  float inv = fast_rcp(se);
  float4 ov;
  ov.x = ex[0] * inv; ov.y = ex[1] * inv; ov.z = ex[2] * inv; ov.w = ex[3] * inv;
  *(float4*)(out + (size_t)i * BN + t * 4) = ov;
}

extern "C" void kernel_launch(void* const* d_in, const int* in_sizes, int n_in,
                              void* d_out, int out_size, void* d_ws, size_t ws_size,
                              hipStream_t stream) {
  (void)in_sizes; (void)n_in; (void)out_size; (void)ws_size;
  const float* X   = (const float*)d_in[0];
  const float* lg  = (const float*)d_in[1];
  const float* adj = (const float*)d_in[2];
  const float* W1  = (const float*)d_in[3];
  const float* b1  = (const float*)d_in[4];
  const float* W2  = (const float*)d_in[5];
  const float* b2  = (const float*)d_in[6];
  float* out = (float*)d_out;                       // [0,B^2): adj_refined, [B^2,2B^2): h_scores
  _Float16* w1h = (_Float16*)d_ws;                  // 17*8192 fp16 = 272 KB (16 steps + label/bias step)
  float* oh = (float*)((char*)d_ws + 17 * 8192 * 2);  // 1024*2 f32

  float* out_hs = out + (size_t)BN * BN;

  prep_kernel<<<dim3(72), dim3(256), 0, stream>>>(W1, b1, lg, w1h, oh);
  // lower-triangle tiles only (h_scores is symmetric): 65x128 rectangle folds onto triangle
  gemm_kernel<<<dim3(65, 128), dim3(256), 0, stream>>>(X, w1h, oh, W2, b2, out_hs);
  softmax_kernel<<<dim3(BN), dim3(256), 0, stream>>>(adj, out_hs, out);
}